// Round 2
// baseline (777.987 us; speedup 1.0000x reference)
//
#include <hip/hip_runtime.h>
#include <math.h>

#define N_DIM 32
#define C_DIM 512
#define K_DIM 64
#define P_DIM 3136

// ws layout (floats): wt 32768 | a_t 6422528 | asum 2048 | vlad 1048576 | gsum 32
// total ~30.0 MB (known-safe: round 1 used 34.3 MB)

// ---------------- prep: wt[c][k] = conv_w[k][c]; zero vlad/asum/gsum ----------------
__global__ __launch_bounds__(256) void k_prep(const float* __restrict__ conv_w,
                                              float* __restrict__ wt,
                                              float* __restrict__ vlad,
                                              float* __restrict__ asum,
                                              float* __restrict__ gsum) {
    const int b = blockIdx.x, t = threadIdx.x;
    const float4 z = make_float4(0.f, 0.f, 0.f, 0.f);
    if (b < 1024) {
        // vlad: 1048576 floats = 262144 float4
        ((float4*)vlad)[b * 256 + t] = z;
    } else if (b < 1056) {
        const int base = (b - 1024) * 1024;
#pragma unroll
        for (int r = 0; r < 4; ++r) {
            int idx = base + r * 256 + t;      // 0..32767
            int c = idx >> 6, k = idx & 63;
            wt[idx] = conv_w[k * C_DIM + c];
        }
    } else {
        ((float4*)asum)[t] = z;                // 2048 floats = 512 float4
        ((float4*)asum)[t + 256] = z;
        if (t < 32) gsum[t] = 0.f;
    }
}

// ---------------- GEMM1 + softmax + asum: a_t[n][p][k] ----------------
// block: 128 pixels x 64 k; thread: 8 pixels x 4 k register tile.
__global__ __launch_bounds__(256) void k_logits(const float* __restrict__ x,
                                                const float* __restrict__ wt,
                                                const float* __restrict__ bias,
                                                float* __restrict__ a_t,
                                                float* __restrict__ asum) {
    __shared__ float xs[64][128];   // [c][p]  32 KB
    __shared__ float wsh[64][64];   // [c][k]  16 KB
    __shared__ float asl[4][64];
    const int tid = threadIdx.x;
    const int n  = blockIdx.y;
    const int p0 = blockIdx.x * 128;          // 25 tiles; last has 64 valid pixels
    const int pg = tid >> 4;                  // 0..15 -> pixels pg*8..+8
    const int kg = tid & 15;                  // 0..15 -> k kg*4..+4

    const float4 b4 = *(const float4*)(bias + kg * 4);
    float acc[8][4];
#pragma unroll
    for (int i = 0; i < 8; ++i) {
        acc[i][0] = b4.x; acc[i][1] = b4.y; acc[i][2] = b4.z; acc[i][3] = b4.w;
    }

    const float* xn = x + (size_t)n * C_DIM * P_DIM;

    for (int cc = 0; cc < C_DIM; cc += 64) {
        // stage x chunk: 64c x 128p = 2048 float4, 8 per thread (coalesced rows)
#pragma unroll
        for (int i = 0; i < 8; ++i) {
            int f = tid + 256 * i;            // 0..2047
            int row = f >> 5;                 // c-local 0..63
            int col = (f & 31) * 4;           // p-local 0..124
            int gcol = p0 + col;
            if (gcol > P_DIM - 4) gcol = P_DIM - 4;   // clamp for the tail tile
            *(float4*)&xs[row][col] =
                *(const float4*)(xn + (size_t)(cc + row) * P_DIM + gcol);
        }
        // stage w chunk: 64c x 64k = 1024 float4, 4 per thread
#pragma unroll
        for (int i = 0; i < 4; ++i) {
            int f = tid + 256 * i;
            int row = f >> 4;
            int col = (f & 15) * 4;
            *(float4*)&wsh[row][col] = *(const float4*)(wt + (cc + row) * K_DIM + col);
        }
        __syncthreads();
#pragma unroll 8
        for (int c = 0; c < 64; ++c) {
            float4 x0 = *(const float4*)&xs[c][pg * 8];
            float4 x1 = *(const float4*)&xs[c][pg * 8 + 4];
            float4 wv = *(const float4*)&wsh[c][kg * 4];
            float xr[8] = {x0.x, x0.y, x0.z, x0.w, x1.x, x1.y, x1.z, x1.w};
            float wr[4] = {wv.x, wv.y, wv.z, wv.w};
#pragma unroll
            for (int i = 0; i < 8; ++i)
#pragma unroll
                for (int j = 0; j < 4; ++j)
                    acc[i][j] = fmaf(xr[i], wr[j], acc[i][j]);
        }
        __syncthreads();
    }

    // softmax per pixel (64 k spread over the 16 lanes sharing pg) + store + asum
    float sk[4] = {0.f, 0.f, 0.f, 0.f};
#pragma unroll
    for (int pi = 0; pi < 8; ++pi) {
        float m = fmaxf(fmaxf(acc[pi][0], acc[pi][1]), fmaxf(acc[pi][2], acc[pi][3]));
        m = fmaxf(m, __shfl_xor(m, 1));
        m = fmaxf(m, __shfl_xor(m, 2));
        m = fmaxf(m, __shfl_xor(m, 4));
        m = fmaxf(m, __shfl_xor(m, 8));
        float e0 = __expf(acc[pi][0] - m);
        float e1 = __expf(acc[pi][1] - m);
        float e2 = __expf(acc[pi][2] - m);
        float e3 = __expf(acc[pi][3] - m);
        float s = e0 + e1 + e2 + e3;
        s += __shfl_xor(s, 1);
        s += __shfl_xor(s, 2);
        s += __shfl_xor(s, 4);
        s += __shfl_xor(s, 8);
        const float inv = 1.0f / s;
        const int p = p0 + pg * 8 + pi;
        if (p < P_DIM) {
            float a0 = e0 * inv, a1 = e1 * inv, a2 = e2 * inv, a3 = e3 * inv;
            *(float4*)(a_t + ((size_t)n * P_DIM + p) * K_DIM + kg * 4) =
                make_float4(a0, a1, a2, a3);
            sk[0] += a0; sk[1] += a1; sk[2] += a2; sk[3] += a3;
        }
    }
#pragma unroll
    for (int j = 0; j < 4; ++j) {
        sk[j] += __shfl_xor(sk[j], 16);
        sk[j] += __shfl_xor(sk[j], 32);
    }
    const int lane = tid & 63;
    const int wv_ = tid >> 6;
    if (lane < 16) *(float4*)&asl[wv_][lane * 4] = make_float4(sk[0], sk[1], sk[2], sk[3]);
    __syncthreads();
    if (tid < 64)
        atomicAdd(&asum[n * K_DIM + tid],
                  asl[0][tid] + asl[1][tid] + asl[2][tid] + asl[3][tid]);
}

// ---------------- GEMM2: vlad[n][c][k] += sum_p x[n][c][p] * a_t[n][p][k] ----------------
// block: 256c x 64k, thread: 8x8 register tile (2 FLOP / LDS byte); p split in 7 slices.
__global__ __launch_bounds__(256) void k_gemm2(const float* __restrict__ x,
                                               const float* __restrict__ a_t,
                                               float* __restrict__ vlad) {
    __shared__ float xs[16][256];   // [p][c] 16 KB
    __shared__ float as[16][64];    // [p][k]  4 KB
    const int tid = threadIdx.x;
    const int c0 = blockIdx.x * 256;          // 0 or 256
    const int n  = blockIdx.y;
    const int p0 = blockIdx.z * 448;          // 7 slices of 448 = 3136
    const int tc = tid >> 3;                  // 0..31 -> c tc*8..+8
    const int tk = tid & 7;                   // 0..7  -> k tk*8..+8

    float acc[8][8];
#pragma unroll
    for (int i = 0; i < 8; ++i)
#pragma unroll
        for (int j = 0; j < 8; ++j) acc[i][j] = 0.f;

    const float* xb = x + ((size_t)n * C_DIM + c0) * P_DIM;
    const float* ab = a_t + (size_t)n * P_DIM * K_DIM;
    const int ar = tid >> 4, ac = (tid & 15) * 4;

    for (int pb = 0; pb < 448; pb += 16) {
        // x: one 16-float row slice per thread (c = c0 + tid)
        const float* gx = xb + (size_t)tid * P_DIM + p0 + pb;
        float4 v0 = *(const float4*)(gx);
        float4 v1 = *(const float4*)(gx + 4);
        float4 v2 = *(const float4*)(gx + 8);
        float4 v3 = *(const float4*)(gx + 12);
        // a: one float4 per thread, direct [p][k] copy
        float4 u = *(const float4*)(ab + (size_t)(p0 + pb + ar) * K_DIM + ac);

        // scatter x into xs[p][c] (conflict-free: lane-consecutive c per instr)
        xs[0][tid]  = v0.x;  xs[1][tid]  = v0.y;  xs[2][tid]  = v0.z;  xs[3][tid]  = v0.w;
        xs[4][tid]  = v1.x;  xs[5][tid]  = v1.y;  xs[6][tid]  = v1.z;  xs[7][tid]  = v1.w;
        xs[8][tid]  = v2.x;  xs[9][tid]  = v2.y;  xs[10][tid] = v2.z;  xs[11][tid] = v2.w;
        xs[12][tid] = v3.x;  xs[13][tid] = v3.y;  xs[14][tid] = v3.z;  xs[15][tid] = v3.w;
        *(float4*)&as[ar][ac] = u;
        __syncthreads();

#pragma unroll 4
        for (int p = 0; p < 16; ++p) {
            float4 a0 = *(const float4*)&as[p][tk * 8];
            float4 a1 = *(const float4*)&as[p][tk * 8 + 4];
            float4 x0 = *(const float4*)&xs[p][tc * 8];
            float4 x1 = *(const float4*)&xs[p][tc * 8 + 4];
            float xr[8] = {x0.x, x0.y, x0.z, x0.w, x1.x, x1.y, x1.z, x1.w};
            float ar8[8] = {a0.x, a0.y, a0.z, a0.w, a1.x, a1.y, a1.z, a1.w};
#pragma unroll
            for (int i = 0; i < 8; ++i)
#pragma unroll
                for (int j = 0; j < 8; ++j)
                    acc[i][j] = fmaf(xr[i], ar8[j], acc[i][j]);
        }
        __syncthreads();
    }

    float* vb = vlad + ((size_t)n * C_DIM + c0 + tc * 8) * K_DIM + tk * 8;
#pragma unroll
    for (int i = 0; i < 8; ++i)
#pragma unroll
        for (int j = 0; j < 8; ++j)
            atomicAdd(&vb[(size_t)i * K_DIM + j], acc[i][j]);
}

// ---------------- intra-norm over k + accumulate global sumsq ----------------
__global__ __launch_bounds__(256) void k_intra(const float* __restrict__ vlad,
                                               const float* __restrict__ cent,
                                               const float* __restrict__ asum,
                                               float* __restrict__ out,
                                               float* __restrict__ gsum) {
    const int w = (blockIdx.x * 256 + threadIdx.x) >> 6;  // (n,c) wave id
    const int lane = threadIdx.x & 63;
    const int n = w >> 9;
    const int c = w & 511;
    const size_t off = ((size_t)n * C_DIM + c) * K_DIM + lane;

    // cent_r[c][k] = centroids_flat[c*64 + k] (row-major reshape, NOT transpose)
    float v = vlad[off] - cent[c * K_DIM + lane] * asum[n * K_DIM + lane];

    float ss = v * v;
#pragma unroll
    for (int o = 32; o > 0; o >>= 1) ss += __shfl_xor(ss, o);

    const float denom = fmaxf(sqrtf(ss), 1e-12f);
    out[off] = v / denom;
    if (lane == 0) atomicAdd(&gsum[n], ss / (denom * denom));
}

// ---------------- final global L2 normalization ----------------
__global__ __launch_bounds__(256) void k_final(float* __restrict__ out,
                                               const float* __restrict__ gsum) {
    const size_t i = (size_t)blockIdx.x * 256 + threadIdx.x;  // 0 .. 2^20-1
    const int n = (int)(i >> 15);                             // C*K = 32768
    const float g = sqrtf(gsum[n]);
    out[i] = out[i] / fmaxf(g, 1e-12f);
}

extern "C" void kernel_launch(void* const* d_in, const int* in_sizes, int n_in,
                              void* d_out, int out_size, void* d_ws, size_t ws_size,
                              hipStream_t stream) {
    const float* x      = (const float*)d_in[0];  // (32,512,56,56)
    const float* cent   = (const float*)d_in[1];  // (64,512) flat
    const float* conv_w = (const float*)d_in[2];  // (64,512)
    const float* conv_b = (const float*)d_in[3];  // (64,)

    float* ws   = (float*)d_ws;
    float* wt   = ws;                                     // 32768
    float* a_t  = wt + 32768;                             // 32*3136*64
    float* asum = a_t + (size_t)N_DIM * P_DIM * K_DIM;    // 2048
    float* vlad = asum + N_DIM * K_DIM;                   // 1048576
    float* gsum = vlad + (size_t)N_DIM * C_DIM * K_DIM;   // 32
    float* out  = (float*)d_out;

    hipLaunchKernelGGL(k_prep,   dim3(1057),      dim3(256), 0, stream, conv_w, wt, vlad, asum, gsum);
    hipLaunchKernelGGL(k_logits, dim3(25, 32),    dim3(256), 0, stream, x, wt, conv_b, a_t, asum);
    hipLaunchKernelGGL(k_gemm2,  dim3(2, 32, 7),  dim3(256), 0, stream, x, a_t, vlad);
    hipLaunchKernelGGL(k_intra,  dim3(4096),      dim3(256), 0, stream, vlad, cent, asum, out, gsum);
    hipLaunchKernelGGL(k_final,  dim3(4096),      dim3(256), 0, stream, out, gsum);
}

// Round 3
// 665.202 us; speedup vs baseline: 1.1695x; 1.1695x over previous
//
#include <hip/hip_runtime.h>
#include <math.h>

#define N_DIM 32
#define C_DIM 512
#define K_DIM 64
#define P_DIM 3136

// ws layout (floats): wt 32768 | a_t 6422528 | asum 2048 | gsum 32 | part S*1048576
// S=14 -> 84.5 MB, S=7 -> 55.2 MB, S=2 -> 33.9 MB (selected from ws_size)

// ---------------- prep: wt[c][k] = conv_w[k][c]; zero asum/gsum ----------------
__global__ __launch_bounds__(256) void k_prep(const float* __restrict__ conv_w,
                                              float* __restrict__ wt,
                                              float* __restrict__ asum,
                                              float* __restrict__ gsum) {
    const int b = blockIdx.x, t = threadIdx.x;
    if (b < 32) {
#pragma unroll
        for (int r = 0; r < 4; ++r) {
            int idx = b * 1024 + r * 256 + t;      // 0..32767
            int c = idx >> 6, k = idx & 63;
            wt[idx] = conv_w[k * C_DIM + c];
        }
    } else {
        const float4 z = make_float4(0.f, 0.f, 0.f, 0.f);
        ((float4*)asum)[t] = z;                    // 2048 floats = 512 float4
        ((float4*)asum)[t + 256] = z;
        if (t < 32) gsum[t] = 0.f;
    }
}

// ---------------- GEMM1 + softmax + asum: a_t[n][p][k] ----------------
// block: 224 pixels x 64 k (14 exact tiles); thread: 7p x 8k register tile.
// register-prefetch double buffering over 32-channel chunks.
__global__ __launch_bounds__(256) void k_logits(const float* __restrict__ x,
                                                const float* __restrict__ wt,
                                                const float* __restrict__ bias,
                                                float* __restrict__ a_t,
                                                float* __restrict__ asum) {
    __shared__ float xs[32][224];   // 28 KB, [c][p]
    __shared__ float wsh[32][64];   //  8 KB, [c][k]
    __shared__ float asl[4][64];
    const int tid = threadIdx.x;
    const int n  = blockIdx.y;
    const int p0 = blockIdx.x * 224;
    const int tp = tid >> 3;        // 0..31 -> pixels p0 + tp + 32*i, i<7
    const int tk = tid & 7;         // 0..7  -> k = tk*8..+8

    float acc[7][8];
    {
        float4 b0 = *(const float4*)(bias + tk * 8);
        float4 b1 = *(const float4*)(bias + tk * 8 + 4);
        float br[8] = {b0.x, b0.y, b0.z, b0.w, b1.x, b1.y, b1.z, b1.w};
#pragma unroll
        for (int i = 0; i < 7; ++i)
#pragma unroll
            for (int j = 0; j < 8; ++j) acc[i][j] = br[j];
    }

    const float* xn = x + (size_t)n * C_DIM * P_DIM + p0;

    float4 xv[7], wv[2];
    // preload chunk cc=0
#pragma unroll
    for (int i = 0; i < 7; ++i) {
        int f = tid + 256 * i;
        xv[i] = *(const float4*)(xn + (size_t)(f / 56) * P_DIM + (f % 56) * 4);
    }
    wv[0] = *(const float4*)(wt + (tid >> 4) * K_DIM + (tid & 15) * 4);
    wv[1] = *(const float4*)(wt + ((tid + 256) >> 4) * K_DIM + (tid & 15) * 4);

    for (int cc = 0; cc < C_DIM; cc += 32) {
        __syncthreads();
#pragma unroll
        for (int i = 0; i < 7; ++i) {
            int f = tid + 256 * i;
            *(float4*)&xs[f / 56][(f % 56) * 4] = xv[i];
        }
        *(float4*)&wsh[tid >> 4][(tid & 15) * 4] = wv[0];
        *(float4*)&wsh[(tid + 256) >> 4][(tid & 15) * 4] = wv[1];
        __syncthreads();

        if (cc + 32 < C_DIM) {
            const float* xc = xn + (size_t)(cc + 32) * P_DIM;
#pragma unroll
            for (int i = 0; i < 7; ++i) {
                int f = tid + 256 * i;
                xv[i] = *(const float4*)(xc + (size_t)(f / 56) * P_DIM + (f % 56) * 4);
            }
            const float* wc = wt + (cc + 32) * K_DIM;
            wv[0] = *(const float4*)(wc + (tid >> 4) * K_DIM + (tid & 15) * 4);
            wv[1] = *(const float4*)(wc + ((tid + 256) >> 4) * K_DIM + (tid & 15) * 4);
        }

#pragma unroll 8
        for (int c = 0; c < 32; ++c) {
            float xr[7];
#pragma unroll
            for (int i = 0; i < 7; ++i) xr[i] = xs[c][tp + 32 * i];   // broadcast, bank=tp
            float4 w0 = *(const float4*)&wsh[c][tk * 8];
            float4 w1 = *(const float4*)&wsh[c][tk * 8 + 4];
            float wr[8] = {w0.x, w0.y, w0.z, w0.w, w1.x, w1.y, w1.z, w1.w};
#pragma unroll
            for (int i = 0; i < 7; ++i)
#pragma unroll
                for (int j = 0; j < 8; ++j)
                    acc[i][j] = fmaf(xr[i], wr[j], acc[i][j]);
        }
    }

    // softmax per pixel: 64 k live in the 8 lanes sharing tp (xor 1,2,4)
    float sk[8] = {0.f, 0.f, 0.f, 0.f, 0.f, 0.f, 0.f, 0.f};
#pragma unroll
    for (int i = 0; i < 7; ++i) {
        float m = acc[i][0];
#pragma unroll
        for (int j = 1; j < 8; ++j) m = fmaxf(m, acc[i][j]);
        m = fmaxf(m, __shfl_xor(m, 1));
        m = fmaxf(m, __shfl_xor(m, 2));
        m = fmaxf(m, __shfl_xor(m, 4));
        float e[8], s = 0.f;
#pragma unroll
        for (int j = 0; j < 8; ++j) { e[j] = __expf(acc[i][j] - m); s += e[j]; }
        s += __shfl_xor(s, 1);
        s += __shfl_xor(s, 2);
        s += __shfl_xor(s, 4);
        const float inv = 1.0f / s;
        float* ap = a_t + ((size_t)n * P_DIM + p0 + tp + 32 * i) * K_DIM + tk * 8;
        float4 o0, o1;
        o0.x = e[0] * inv; o0.y = e[1] * inv; o0.z = e[2] * inv; o0.w = e[3] * inv;
        o1.x = e[4] * inv; o1.y = e[5] * inv; o1.z = e[6] * inv; o1.w = e[7] * inv;
        *(float4*)ap = o0;
        *(float4*)(ap + 4) = o1;
        sk[0] += o0.x; sk[1] += o0.y; sk[2] += o0.z; sk[3] += o0.w;
        sk[4] += o1.x; sk[5] += o1.y; sk[6] += o1.z; sk[7] += o1.w;
    }
    // reduce over tp (bits 3,4,5 of lane) then across the 4 waves via LDS
#pragma unroll
    for (int j = 0; j < 8; ++j) {
        sk[j] += __shfl_xor(sk[j], 8);
        sk[j] += __shfl_xor(sk[j], 16);
        sk[j] += __shfl_xor(sk[j], 32);
    }
    const int lane = tid & 63, wv_ = tid >> 6;
    if (lane < 8) {
#pragma unroll
        for (int j = 0; j < 8; ++j) asl[wv_][lane * 8 + j] = sk[j];
    }
    __syncthreads();
    if (tid < 64)
        atomicAdd(&asum[n * K_DIM + tid],
                  asl[0][tid] + asl[1][tid] + asl[2][tid] + asl[3][tid]);
}

// ---------------- GEMM2: part[s][n][c][k] = sum_{p in slice s} x[n][c][p]*a_t[n][p][k] ----
// block: 128c x 64k, 128 threads, 8x8/thread; plain stores (no atomics);
// register-prefetch double buffering over 16-p chunks.
__global__ __launch_bounds__(128) void k_gemm2(const float* __restrict__ x,
                                               const float* __restrict__ a_t,
                                               float* __restrict__ part,
                                               int pslice) {
    __shared__ float xs[16][132];   // [p][c], pad 128->132 (stores 2-way max)
    __shared__ float as[16][64];    // [p][k]
    const int tid = threadIdx.x;
    const int c0 = blockIdx.x * 128;
    const int n  = blockIdx.y;
    const int s  = blockIdx.z;
    const int p0 = s * pslice;
    const int tc = tid >> 3;        // 0..15 -> c = c0 + tc*8
    const int tk = tid & 7;         // 0..7  -> k = tk*8

    float acc[8][8];
#pragma unroll
    for (int i = 0; i < 8; ++i)
#pragma unroll
        for (int j = 0; j < 8; ++j) acc[i][j] = 0.f;

    const float* xb = x + ((size_t)n * C_DIM + c0) * P_DIM + p0;
    const float* ab = a_t + ((size_t)n * P_DIM + p0) * K_DIM;

    float4 xv[4], av[2];
#pragma unroll
    for (int i = 0; i < 4; ++i) {
        int f = tid + 128 * i;
        xv[i] = *(const float4*)(xb + (size_t)(f >> 2) * P_DIM + (f & 3) * 4);
    }
#pragma unroll
    for (int i = 0; i < 2; ++i) {
        int f = tid + 128 * i;
        av[i] = *(const float4*)(ab + (size_t)(f >> 4) * K_DIM + (f & 15) * 4);
    }

    for (int pb = 0; pb < pslice; pb += 16) {
        __syncthreads();
#pragma unroll
        for (int i = 0; i < 4; ++i) {
            int f = tid + 128 * i;
            int c = f >> 2, pe = (f & 3) * 4;
            xs[pe + 0][c] = xv[i].x;
            xs[pe + 1][c] = xv[i].y;
            xs[pe + 2][c] = xv[i].z;
            xs[pe + 3][c] = xv[i].w;
        }
#pragma unroll
        for (int i = 0; i < 2; ++i) {
            int f = tid + 128 * i;
            *(float4*)&as[f >> 4][(f & 15) * 4] = av[i];
        }
        __syncthreads();

        if (pb + 16 < pslice) {
            const float* xc = xb + pb + 16;
            const float* ac = ab + (size_t)(pb + 16) * K_DIM;
#pragma unroll
            for (int i = 0; i < 4; ++i) {
                int f = tid + 128 * i;
                xv[i] = *(const float4*)(xc + (size_t)(f >> 2) * P_DIM + (f & 3) * 4);
            }
#pragma unroll
            for (int i = 0; i < 2; ++i) {
                int f = tid + 128 * i;
                av[i] = *(const float4*)(ac + (size_t)(f >> 4) * K_DIM + (f & 15) * 4);
            }
        }

#pragma unroll 4
        for (int p = 0; p < 16; ++p) {
            float4 x0 = *(const float4*)&xs[p][tc * 8];
            float4 x1 = *(const float4*)&xs[p][tc * 8 + 4];
            float4 a0 = *(const float4*)&as[p][tk * 8];
            float4 a1 = *(const float4*)&as[p][tk * 8 + 4];
            float xr[8] = {x0.x, x0.y, x0.z, x0.w, x1.x, x1.y, x1.z, x1.w};
            float ar[8] = {a0.x, a0.y, a0.z, a0.w, a1.x, a1.y, a1.z, a1.w};
#pragma unroll
            for (int i = 0; i < 8; ++i)
#pragma unroll
                for (int j = 0; j < 8; ++j)
                    acc[i][j] = fmaf(xr[i], ar[j], acc[i][j]);
        }
    }

    float* po = part + (((size_t)s * N_DIM + n) * C_DIM + c0 + tc * 8) * K_DIM + tk * 8;
#pragma unroll
    for (int i = 0; i < 8; ++i) {
        float4 o0, o1;
        o0.x = acc[i][0]; o0.y = acc[i][1]; o0.z = acc[i][2]; o0.w = acc[i][3];
        o1.x = acc[i][4]; o1.y = acc[i][5]; o1.z = acc[i][6]; o1.w = acc[i][7];
        *(float4*)&po[(size_t)i * K_DIM] = o0;
        *(float4*)&po[(size_t)i * K_DIM + 4] = o1;
    }
}

// ---------------- slice-reduce + subtract + intra-norm over k + global sumsq ----------------
__global__ __launch_bounds__(256) void k_intra(const float* __restrict__ part,
                                               const float* __restrict__ cent,
                                               const float* __restrict__ asum,
                                               float* __restrict__ out,
                                               float* __restrict__ gsum,
                                               int S) {
    const int w = (blockIdx.x * 256 + threadIdx.x) >> 6;  // (n,c) wave id
    const int lane = threadIdx.x & 63;
    const int n = w >> 9;
    const int c = w & 511;
    const size_t off = ((size_t)n * C_DIM + c) * K_DIM + lane;
    const size_t stride = (size_t)N_DIM * C_DIM * K_DIM;

    float v = 0.f;
    for (int s = 0; s < S; ++s) v += part[s * stride + off];
    // cent_r[c][k] = centroids_flat[c*64 + k] (row-major reshape, NOT transpose)
    v -= cent[c * K_DIM + lane] * asum[n * K_DIM + lane];

    float ss = v * v;
#pragma unroll
    for (int o = 32; o > 0; o >>= 1) ss += __shfl_xor(ss, o);

    const float denom = fmaxf(sqrtf(ss), 1e-12f);
    out[off] = v / denom;
    if (lane == 0) atomicAdd(&gsum[n], ss / (denom * denom));
}

// ---------------- final global L2 normalization ----------------
__global__ __launch_bounds__(256) void k_final(float* __restrict__ out,
                                               const float* __restrict__ gsum) {
    const size_t i = (size_t)blockIdx.x * 256 + threadIdx.x;  // 0 .. 2^20-1
    const int n = (int)(i >> 15);                             // C*K = 32768
    const float g = sqrtf(gsum[n]);
    out[i] = out[i] / fmaxf(g, 1e-12f);
}

extern "C" void kernel_launch(void* const* d_in, const int* in_sizes, int n_in,
                              void* d_out, int out_size, void* d_ws, size_t ws_size,
                              hipStream_t stream) {
    const float* x      = (const float*)d_in[0];  // (32,512,56,56)
    const float* cent   = (const float*)d_in[1];  // (64,512) flat
    const float* conv_w = (const float*)d_in[2];  // (64,512)
    const float* conv_b = (const float*)d_in[3];  // (64,)

    float* ws   = (float*)d_ws;
    float* wt   = ws;                                     // 32768
    float* a_t  = wt + 32768;                             // 32*3136*64
    float* asum = a_t + (size_t)N_DIM * P_DIM * K_DIM;    // 2048
    float* gsum = asum + N_DIM * K_DIM;                   // 32
    float* part = gsum + 32;                              // S * 1048576
    float* out  = (float*)d_out;

    // slice count from ws budget (deterministic per process -> graph-safe)
    const size_t base_f = 32768 + (size_t)N_DIM * P_DIM * K_DIM + 2048 + 32;
    const size_t cxk = (size_t)N_DIM * C_DIM * K_DIM;     // 1048576
    int S = 14;                                           // pslice 224
    if (ws_size < (base_f + 14 * cxk) * 4) S = 7;         // pslice 448
    if (ws_size < (base_f + 7 * cxk) * 4) S = 2;          // pslice 1568
    const int pslice = P_DIM / S;

    hipLaunchKernelGGL(k_prep,   dim3(33),        dim3(256), 0, stream, conv_w, wt, asum, gsum);
    hipLaunchKernelGGL(k_logits, dim3(14, 32),    dim3(256), 0, stream, x, wt, conv_b, a_t, asum);
    hipLaunchKernelGGL(k_gemm2,  dim3(4, 32, S),  dim3(128), 0, stream, x, a_t, part, pslice);
    hipLaunchKernelGGL(k_intra,  dim3(4096),      dim3(256), 0, stream, part, cent, asum, out, gsum, S);
    hipLaunchKernelGGL(k_final,  dim3(4096),      dim3(256), 0, stream, out, gsum);
}

// Round 4
// 506.495 us; speedup vs baseline: 1.5360x; 1.3133x over previous
//
#include <hip/hip_runtime.h>
#include <math.h>

#define N_DIM 32
#define C_DIM 512
#define K_DIM 64
#define P_DIM 3136

// ws layout (floats): wt 32768 | a_t 6422528 | asum 2048 | asum_part 28672 |
//                     gsum 32 | ssb 16384 | part S*1048576
// S=14 -> 84.8 MB, S=7 -> 55.4 MB, S=2 -> 34.1 MB (selected from ws_size)

// ---------------- prep: wt[c][k] = conv_w[k][c] ----------------
__global__ __launch_bounds__(256) void k_prep(const float* __restrict__ conv_w,
                                              float* __restrict__ wt) {
    const int b = blockIdx.x, t = threadIdx.x;
#pragma unroll
    for (int r = 0; r < 4; ++r) {
        int idx = b * 1024 + r * 256 + t;      // 0..32767
        int c = idx >> 6, k = idx & 63;
        wt[idx] = conv_w[k * C_DIM + c];
    }
}

// ---------------- GEMM1 + softmax + asum partials: a_t[n][p][k] ----------------
// block: 224 pixels x 64 k (14 exact tiles); thread: 7p x 8k register tile.
// register-prefetch double buffering over 32-channel chunks. NO global atomics.
__global__ __launch_bounds__(256) void k_logits(const float* __restrict__ x,
                                                const float* __restrict__ wt,
                                                const float* __restrict__ bias,
                                                float* __restrict__ a_t,
                                                float* __restrict__ asum_part) {
    __shared__ float xs[32][224];   // 28 KB, [c][p]
    __shared__ float wsh[32][64];   //  8 KB, [c][k]
    __shared__ float asl[4][64];
    const int tid = threadIdx.x;
    const int n  = blockIdx.y;
    const int pblk = blockIdx.x;
    const int p0 = pblk * 224;
    const int tp = tid >> 3;        // 0..31 -> pixels p0 + tp + 32*i, i<7
    const int tk = tid & 7;         // 0..7  -> k = tk*8..+8

    float acc[7][8];
    {
        float4 b0 = *(const float4*)(bias + tk * 8);
        float4 b1 = *(const float4*)(bias + tk * 8 + 4);
        float br[8] = {b0.x, b0.y, b0.z, b0.w, b1.x, b1.y, b1.z, b1.w};
#pragma unroll
        for (int i = 0; i < 7; ++i)
#pragma unroll
            for (int j = 0; j < 8; ++j) acc[i][j] = br[j];
    }

    const float* xn = x + (size_t)n * C_DIM * P_DIM + p0;

    float4 xv[7], wv[2];
#pragma unroll
    for (int i = 0; i < 7; ++i) {
        int f = tid + 256 * i;
        xv[i] = *(const float4*)(xn + (size_t)(f / 56) * P_DIM + (f % 56) * 4);
    }
    wv[0] = *(const float4*)(wt + (tid >> 4) * K_DIM + (tid & 15) * 4);
    wv[1] = *(const float4*)(wt + ((tid + 256) >> 4) * K_DIM + (tid & 15) * 4);

    for (int cc = 0; cc < C_DIM; cc += 32) {
        __syncthreads();
#pragma unroll
        for (int i = 0; i < 7; ++i) {
            int f = tid + 256 * i;
            *(float4*)&xs[f / 56][(f % 56) * 4] = xv[i];
        }
        *(float4*)&wsh[tid >> 4][(tid & 15) * 4] = wv[0];
        *(float4*)&wsh[(tid + 256) >> 4][(tid & 15) * 4] = wv[1];
        __syncthreads();

        if (cc + 32 < C_DIM) {
            const float* xc = xn + (size_t)(cc + 32) * P_DIM;
#pragma unroll
            for (int i = 0; i < 7; ++i) {
                int f = tid + 256 * i;
                xv[i] = *(const float4*)(xc + (size_t)(f / 56) * P_DIM + (f % 56) * 4);
            }
            const float* wc = wt + (cc + 32) * K_DIM;
            wv[0] = *(const float4*)(wc + (tid >> 4) * K_DIM + (tid & 15) * 4);
            wv[1] = *(const float4*)(wc + ((tid + 256) >> 4) * K_DIM + (tid & 15) * 4);
        }

#pragma unroll 8
        for (int c = 0; c < 32; ++c) {
            float xr[7];
#pragma unroll
            for (int i = 0; i < 7; ++i) xr[i] = xs[c][tp + 32 * i];   // broadcast, bank=tp
            float4 w0 = *(const float4*)&wsh[c][tk * 8];
            float4 w1 = *(const float4*)&wsh[c][tk * 8 + 4];
            float wr[8] = {w0.x, w0.y, w0.z, w0.w, w1.x, w1.y, w1.z, w1.w};
#pragma unroll
            for (int i = 0; i < 7; ++i)
#pragma unroll
                for (int j = 0; j < 8; ++j)
                    acc[i][j] = fmaf(xr[i], wr[j], acc[i][j]);
        }
    }

    // softmax per pixel: 64 k live in the 8 lanes sharing tp (xor 1,2,4)
    float sk[8] = {0.f, 0.f, 0.f, 0.f, 0.f, 0.f, 0.f, 0.f};
#pragma unroll
    for (int i = 0; i < 7; ++i) {
        float m = acc[i][0];
#pragma unroll
        for (int j = 1; j < 8; ++j) m = fmaxf(m, acc[i][j]);
        m = fmaxf(m, __shfl_xor(m, 1));
        m = fmaxf(m, __shfl_xor(m, 2));
        m = fmaxf(m, __shfl_xor(m, 4));
        float e[8], s = 0.f;
#pragma unroll
        for (int j = 0; j < 8; ++j) { e[j] = __expf(acc[i][j] - m); s += e[j]; }
        s += __shfl_xor(s, 1);
        s += __shfl_xor(s, 2);
        s += __shfl_xor(s, 4);
        const float inv = 1.0f / s;
        float* ap = a_t + ((size_t)n * P_DIM + p0 + tp + 32 * i) * K_DIM + tk * 8;
        float4 o0, o1;
        o0.x = e[0] * inv; o0.y = e[1] * inv; o0.z = e[2] * inv; o0.w = e[3] * inv;
        o1.x = e[4] * inv; o1.y = e[5] * inv; o1.z = e[6] * inv; o1.w = e[7] * inv;
        *(float4*)ap = o0;
        *(float4*)(ap + 4) = o1;
        sk[0] += o0.x; sk[1] += o0.y; sk[2] += o0.z; sk[3] += o0.w;
        sk[4] += o1.x; sk[5] += o1.y; sk[6] += o1.z; sk[7] += o1.w;
    }
    // reduce over tp (bits 3,4,5 of lane) then across the 4 waves via LDS
#pragma unroll
    for (int j = 0; j < 8; ++j) {
        sk[j] += __shfl_xor(sk[j], 8);
        sk[j] += __shfl_xor(sk[j], 16);
        sk[j] += __shfl_xor(sk[j], 32);
    }
    const int lane = tid & 63, wv_ = tid >> 6;
    if (lane < 8) {
#pragma unroll
        for (int j = 0; j < 8; ++j) asl[wv_][lane * 8 + j] = sk[j];
    }
    __syncthreads();
    if (tid < 64)
        asum_part[((size_t)n * 14 + pblk) * K_DIM + tid] =
            asl[0][tid] + asl[1][tid] + asl[2][tid] + asl[3][tid];
}

// ---------------- asum[n][k] = sum_b asum_part[n][b][k] ----------------
__global__ __launch_bounds__(256) void k_red(const float* __restrict__ asum_part,
                                             float* __restrict__ asum) {
    const int idx = blockIdx.x * 256 + threadIdx.x;   // 0..2047
    const int n = idx >> 6, k = idx & 63;
    float s = 0.f;
#pragma unroll
    for (int b = 0; b < 14; ++b)
        s += asum_part[((size_t)n * 14 + b) * K_DIM + k];
    asum[idx] = s;
}

// ---------------- GEMM2: part[s][n][c][k] = sum_{p in slice s} x[n][c][p]*a_t[n][p][k] ----
// block: 128c x 64k, 128 threads, 8x8/thread; plain stores (no atomics);
// register-prefetch double buffering over 16-p chunks.
__global__ __launch_bounds__(128) void k_gemm2(const float* __restrict__ x,
                                               const float* __restrict__ a_t,
                                               float* __restrict__ part,
                                               int pslice) {
    __shared__ float xs[16][132];   // [p][c], pad 128->132 (stores 2-way max)
    __shared__ float as[16][64];    // [p][k]
    const int tid = threadIdx.x;
    const int c0 = blockIdx.x * 128;
    const int n  = blockIdx.y;
    const int s  = blockIdx.z;
    const int p0 = s * pslice;
    const int tc = tid >> 3;        // 0..15 -> c = c0 + tc*8
    const int tk = tid & 7;         // 0..7  -> k = tk*8

    float acc[8][8];
#pragma unroll
    for (int i = 0; i < 8; ++i)
#pragma unroll
        for (int j = 0; j < 8; ++j) acc[i][j] = 0.f;

    const float* xb = x + ((size_t)n * C_DIM + c0) * P_DIM + p0;
    const float* ab = a_t + ((size_t)n * P_DIM + p0) * K_DIM;

    float4 xv[4], av[2];
#pragma unroll
    for (int i = 0; i < 4; ++i) {
        int f = tid + 128 * i;
        xv[i] = *(const float4*)(xb + (size_t)(f >> 2) * P_DIM + (f & 3) * 4);
    }
#pragma unroll
    for (int i = 0; i < 2; ++i) {
        int f = tid + 128 * i;
        av[i] = *(const float4*)(ab + (size_t)(f >> 4) * K_DIM + (f & 15) * 4);
    }

    for (int pb = 0; pb < pslice; pb += 16) {
        __syncthreads();
#pragma unroll
        for (int i = 0; i < 4; ++i) {
            int f = tid + 128 * i;
            int c = f >> 2, pe = (f & 3) * 4;
            xs[pe + 0][c] = xv[i].x;
            xs[pe + 1][c] = xv[i].y;
            xs[pe + 2][c] = xv[i].z;
            xs[pe + 3][c] = xv[i].w;
        }
#pragma unroll
        for (int i = 0; i < 2; ++i) {
            int f = tid + 128 * i;
            *(float4*)&as[f >> 4][(f & 15) * 4] = av[i];
        }
        __syncthreads();

        if (pb + 16 < pslice) {
            const float* xc = xb + pb + 16;
            const float* ac = ab + (size_t)(pb + 16) * K_DIM;
#pragma unroll
            for (int i = 0; i < 4; ++i) {
                int f = tid + 128 * i;
                xv[i] = *(const float4*)(xc + (size_t)(f >> 2) * P_DIM + (f & 3) * 4);
            }
#pragma unroll
            for (int i = 0; i < 2; ++i) {
                int f = tid + 128 * i;
                av[i] = *(const float4*)(ac + (size_t)(f >> 4) * K_DIM + (f & 15) * 4);
            }
        }

#pragma unroll 4
        for (int p = 0; p < 16; ++p) {
            float4 x0 = *(const float4*)&xs[p][tc * 8];
            float4 x1 = *(const float4*)&xs[p][tc * 8 + 4];
            float4 a0 = *(const float4*)&as[p][tk * 8];
            float4 a1 = *(const float4*)&as[p][tk * 8 + 4];
            float xr[8] = {x0.x, x0.y, x0.z, x0.w, x1.x, x1.y, x1.z, x1.w};
            float ar[8] = {a0.x, a0.y, a0.z, a0.w, a1.x, a1.y, a1.z, a1.w};
#pragma unroll
            for (int i = 0; i < 8; ++i)
#pragma unroll
                for (int j = 0; j < 8; ++j)
                    acc[i][j] = fmaf(xr[i], ar[j], acc[i][j]);
        }
    }

    float* po = part + (((size_t)s * N_DIM + n) * C_DIM + c0 + tc * 8) * K_DIM + tk * 8;
#pragma unroll
    for (int i = 0; i < 8; ++i) {
        float4 o0, o1;
        o0.x = acc[i][0]; o0.y = acc[i][1]; o0.z = acc[i][2]; o0.w = acc[i][3];
        o1.x = acc[i][4]; o1.y = acc[i][5]; o1.z = acc[i][6]; o1.w = acc[i][7];
        *(float4*)&po[(size_t)i * K_DIM] = o0;
        *(float4*)&po[(size_t)i * K_DIM + 4] = o1;
    }
}

// ---------------- slice-reduce + subtract + intra-norm over k; ss -> ssb (no atomics) ----
template <int S>
__global__ __launch_bounds__(256) void k_intra(const float* __restrict__ part,
                                               const float* __restrict__ cent,
                                               const float* __restrict__ asum,
                                               float* __restrict__ out,
                                               float* __restrict__ ssb) {
    const int w = (blockIdx.x * 256 + threadIdx.x) >> 6;  // (n,c) wave id
    const int lane = threadIdx.x & 63;
    const int n = w >> 9;
    const int c = w & 511;
    const size_t off = ((size_t)n * C_DIM + c) * K_DIM + lane;
    const size_t stride = (size_t)N_DIM * C_DIM * K_DIM;

    float v = 0.f;
#pragma unroll
    for (int s = 0; s < S; ++s) v += part[s * stride + off];
    // cent_r[c][k] = centroids_flat[c*64 + k] (row-major reshape, NOT transpose)
    v -= cent[c * K_DIM + lane] * asum[n * K_DIM + lane];

    float ss = v * v;
#pragma unroll
    for (int o = 32; o > 0; o >>= 1) ss += __shfl_xor(ss, o);

    const float denom = fmaxf(sqrtf(ss), 1e-12f);
    out[off] = v / denom;
    if (lane == 0) ssb[w] = ss / (denom * denom);   // == clipped ratio, sums to gsum
}

// ---------------- gsum[n] = sum_c ssb[n][c] ----------------
__global__ __launch_bounds__(256) void k_gsum(const float* __restrict__ ssb,
                                              float* __restrict__ gsum) {
    const int n = blockIdx.x, t = threadIdx.x;
    float s = ssb[n * C_DIM + t] + ssb[n * C_DIM + t + 256];
    __shared__ float red[256];
    red[t] = s;
    __syncthreads();
    for (int o = 128; o > 0; o >>= 1) {
        if (t < o) red[t] += red[t + o];
        __syncthreads();
    }
    if (t == 0) gsum[n] = red[0];
}

// ---------------- final global L2 normalization ----------------
__global__ __launch_bounds__(256) void k_final(float* __restrict__ out,
                                               const float* __restrict__ gsum) {
    const size_t i = (size_t)blockIdx.x * 256 + threadIdx.x;  // 0 .. 2^20-1
    const int n = (int)(i >> 15);                             // C*K = 32768
    const float g = sqrtf(gsum[n]);
    out[i] = out[i] / fmaxf(g, 1e-12f);
}

extern "C" void kernel_launch(void* const* d_in, const int* in_sizes, int n_in,
                              void* d_out, int out_size, void* d_ws, size_t ws_size,
                              hipStream_t stream) {
    const float* x      = (const float*)d_in[0];  // (32,512,56,56)
    const float* cent   = (const float*)d_in[1];  // (64,512) flat
    const float* conv_w = (const float*)d_in[2];  // (64,512)
    const float* conv_b = (const float*)d_in[3];  // (64,)

    float* ws    = (float*)d_ws;
    float* wt    = ws;                                     // 32768
    float* a_t   = wt + 32768;                             // 32*3136*64
    float* asum  = a_t + (size_t)N_DIM * P_DIM * K_DIM;    // 2048
    float* apart = asum + 2048;                            // 32*14*64 = 28672
    float* gsum  = apart + 28672;                          // 32
    float* ssb   = gsum + 32;                              // 16384
    float* part  = ssb + 16384;                            // S * 1048576
    float* out   = (float*)d_out;

    const size_t base_f = (size_t)(part - ws);
    const size_t cxk = (size_t)N_DIM * C_DIM * K_DIM;      // 1048576
    int S = 14;
    if (ws_size < (base_f + 14 * cxk) * 4) S = 7;
    if (ws_size < (base_f + 7 * cxk) * 4) S = 2;
    const int pslice = P_DIM / S;

    hipLaunchKernelGGL(k_prep,   dim3(32),        dim3(256), 0, stream, conv_w, wt);
    hipLaunchKernelGGL(k_logits, dim3(14, 32),    dim3(256), 0, stream, x, wt, conv_b, a_t, apart);
    hipLaunchKernelGGL(k_red,    dim3(8),         dim3(256), 0, stream, apart, asum);
    hipLaunchKernelGGL(k_gemm2,  dim3(4, 32, S),  dim3(128), 0, stream, x, a_t, part, pslice);
    if (S == 14)
        hipLaunchKernelGGL(k_intra<14>, dim3(4096), dim3(256), 0, stream, part, cent, asum, out, ssb);
    else if (S == 7)
        hipLaunchKernelGGL(k_intra<7>,  dim3(4096), dim3(256), 0, stream, part, cent, asum, out, ssb);
    else
        hipLaunchKernelGGL(k_intra<2>,  dim3(4096), dim3(256), 0, stream, part, cent, asum, out, ssb);
    hipLaunchKernelGGL(k_gsum,   dim3(32),        dim3(256), 0, stream, ssb, gsum);
    hipLaunchKernelGGL(k_final,  dim3(4096),      dim3(256), 0, stream, out, gsum);
}